// Round 12
// baseline (204.866 us; speedup 1.0000x reference)
//
#include <hip/hip_runtime.h>

#define NB   1024
#define SINQ 256
#define SPRQ 128
#define HIDQ 512

// pos_enc: emb[:, :3] = sin(pos * inv_freq[c]); inv_freq[c] = 10000^(-2c/256)
#define PEF1  0.93057207f
#define PEF2  0.86596438f
#define LOG2E 1.44269504089f
// q pre-scale: 1/sqrt(3) * log2(e)
#define QS    0.83298066476f

typedef _Float16 h2 __attribute__((ext_vector_type(2)));

#if defined(__has_builtin) && __has_builtin(__builtin_amdgcn_exp2f)
#define EXP2(x) __builtin_amdgcn_exp2f(x)
#else
#define EXP2(x) exp2f(x)
#endif

#if defined(__has_builtin) && __has_builtin(__builtin_amdgcn_fdot2)
#define FDOT2(a, b, c) __builtin_amdgcn_fdot2((a), (b), (c), false)
#else
__device__ __forceinline__ float fdot2_sw(h2 a, h2 b, float c) {
  return fmaf((float)a.x, (float)b.x, fmaf((float)a.y, (float)b.y, c));
}
#define FDOT2(a, b, c) fdot2_sw((a), (b), (c))
#endif

__device__ __forceinline__ unsigned pk16(float a, float b) {
  h2 v; v.x = (_Float16)a; v.y = (_Float16)b;
  return __builtin_bit_cast(unsigned, v);
}
__device__ __forceinline__ h2 uph(unsigned u) { return __builtin_bit_cast(h2, u); }

__device__ __forceinline__ h2 relu2(h2 z) {
#if defined(__has_builtin) && __has_builtin(__builtin_elementwise_max)
  h2 zz; zz.x = (_Float16)0.f; zz.y = (_Float16)0.f;
  return __builtin_elementwise_max(z, zz);
#else
  z.x = z.x > (_Float16)0.f ? z.x : (_Float16)0.f;
  z.y = z.y > (_Float16)0.f ? z.y : (_Float16)0.f;
  return z;
#endif
}

// register-only selects (v_cndmask chains) -- NEVER index private arrays
// with a RUNTIME value (scratch demotion = HBM). Constant indices inside
// fully-unrolled loops are fine (SROA handles them).
// R8/R9/R10 lesson: 512-thread (8-wave) workgroups spill massively on this
// barrier-heavy kernel regardless of __launch_bounds__ cap. 256-thr only.
__device__ __forceinline__ float sel4(float a, float b, float c, float d, int s) {
  float r = a;
  r = (s == 1) ? b : r;
  r = (s == 2) ? c : r;
  r = (s == 3) ? d : r;
  return r;
}

// xor-combines over slot lanes
#define C4(v) { v += __shfl_xor((v), 1, 64); v += __shfl_xor((v), 2, 64); }
#define C8(v) { v += __shfl_xor((v), 1, 64); v += __shfl_xor((v), 2, 64); \
                v += __shfl_xor((v), 4, 64); }

// Block-wide (256 thr) mean/rstd over nelem values.
__device__ __forceinline__ void block_stats(float s1, float s2, float* sRed,
                                            int tid, float nelem,
                                            float& mean, float& rstd) {
#pragma unroll
  for (int off = 32; off > 0; off >>= 1) {
    s1 += __shfl_xor(s1, off, 64);
    s2 += __shfl_xor(s2, off, 64);
  }
  __syncthreads();
  if ((tid & 63) == 0) {
    sRed[((tid >> 6) << 1) + 0] = s1;
    sRed[((tid >> 6) << 1) + 1] = s2;
  }
  __syncthreads();
  float t1 = sRed[0] + sRed[2] + sRed[4] + sRed[6];
  float t2 = sRed[1] + sRed[3] + sRed[5] + sRed[7];
  mean = t1 / nelem;
  rstd = rsqrtf(t2 / nelem - mean * mean + 1e-5f);
}

// Pack f16 FFN pair-records and the sin() table.
__global__ __launch_bounds__(256) void pack_tabs(
    const float* __restrict__ ew1, const float* __restrict__ eb1,
    const float* __restrict__ ew2,
    const float* __restrict__ dw1, const float* __restrict__ db1,
    const float* __restrict__ dw2,
    uint4* __restrict__ fE, uint4* __restrict__ fD, float4* __restrict__ pe)
{
  const int t = threadIdx.x;        // pair index, 0..255
  const int k0 = 2 * t, k1 = 2 * t + 1;
  fE[2 * t] = make_uint4(pk16(ew1[3 * k0], ew1[3 * k1]),
                         pk16(ew1[3 * k0 + 1], ew1[3 * k1 + 1]),
                         pk16(ew1[3 * k0 + 2], ew1[3 * k1 + 2]),
                         pk16(eb1[k0], eb1[k1]));
  fE[2 * t + 1] = make_uint4(pk16(ew2[k0], ew2[k1]),
                             pk16(ew2[HIDQ + k0], ew2[HIDQ + k1]),
                             pk16(ew2[2 * HIDQ + k0], ew2[2 * HIDQ + k1]), 0u);
  fD[2 * t] = make_uint4(pk16(dw1[3 * k0], dw1[3 * k1]),
                         pk16(dw1[3 * k0 + 1], dw1[3 * k1 + 1]),
                         pk16(dw1[3 * k0 + 2], dw1[3 * k1 + 2]),
                         pk16(db1[k0], db1[k1]));
  fD[2 * t + 1] = make_uint4(pk16(dw2[k0], dw2[k1]),
                             pk16(dw2[HIDQ + k0], dw2[HIDQ + k1]),
                             pk16(dw2[2 * HIDQ + k0], dw2[2 * HIDQ + k1]), 0u);
  const float p = (float)t;
  pe[t] = make_float4(sinf(p), sinf(p * PEF1), sinf(p * PEF2), 0.f);
}

// One 256-thr block per batch element.
// Encoder: 4-way slot split (s = t&3), Q=4 rows/thread.
// Decoder: 8-way slot split (s8 = t&7), Q=4 rows/thread (2x lane dup) --
// halves decoder LDS stream reads + loop iterations vs the Q=2 variant.
__global__ __launch_bounds__(256, 4) void fused_fwd(
    const float* __restrict__ X, const float* __restrict__ T,
    const float* __restrict__ einw, const float* __restrict__ einb,
    const float* __restrict__ eow,  const float* __restrict__ eob,
    const float* __restrict__ eln1w, const float* __restrict__ eln1b,
    const float* __restrict__ eb2,
    const float* __restrict__ eln2w, const float* __restrict__ eln2b,
    const float* __restrict__ a1w, const float* __restrict__ a1b,
    const float* __restrict__ a1ow, const float* __restrict__ a1ob,
    const float* __restrict__ dln1w, const float* __restrict__ dln1b,
    const float* __restrict__ a2w, const float* __restrict__ a2b,
    const float* __restrict__ a2ow, const float* __restrict__ a2ob,
    const float* __restrict__ db2,
    const float* __restrict__ dln3w, const float* __restrict__ dln3b,
    const uint4* __restrict__ fE, const uint4* __restrict__ fD,
    const float4* __restrict__ pe,
    float* __restrict__ out)
{
  __shared__ uint4 sFE[2 * 256];   // 8 KB enc FFN pair-records
  __shared__ uint4 sFD[2 * 256];   // 8 KB dec FFN pair-records
  __shared__ uint2 sEP[SINQ];      // 2 KB f16 p_X rows {(p0,p1),(p2,1)}
  __shared__ uint2 sDP[SPRQ];      // 1 KB f16 p_T rows
  __shared__ uint2 sCE[SINQ];      // 2 KB f16 enc_out rows
  __shared__ float sRed[8];

  const int b = blockIdx.x;
  const int t = threadIdx.x;
  const int lane = t & 63;
  const int s = t & 3;             // enc slot
  const int g = t >> 2;            // enc row-group (0..63)

  // ---- stage tables + p-rows
  sFE[t] = fE[t]; sFE[t + 256] = fE[t + 256];
  sFD[t] = fD[t]; sFD[t + 256] = fD[t + 256];
  {
    const float4 peT = pe[t];
    const float* xr = X + (size_t)b * SINQ * 3 + 3 * t;
    sEP[t] = make_uint2(pk16(xr[0] + peT.x, xr[1] + peT.y),
                        pk16(xr[2] + peT.z, 1.f));
    if (t < SPRQ) {
      const float* tr = T + (size_t)b * SPRQ * 3 + 3 * t;
      sDP[t] = make_uint2(pk16(tr[0] + peT.x, tr[1] + peT.y),
                          pk16(tr[2] + peT.z, 1.f));
    }
  }
  __syncthreads();

  // ================= ENCODER =================
  unsigned qa[4], qb[4];
#pragma unroll
  for (int m = 0; m < 4; ++m) {
    const uint2 pr = sEP[g + 64 * m];
    const h2 ha = uph(pr.x), hb = uph(pr.y);
    const float pp0 = (float)ha.x, pp1 = (float)ha.y, pp2 = (float)hb.x;
    const float q0 = (einw[0] * pp0 + einw[1] * pp1 + einw[2] * pp2 + einb[0]) * QS;
    const float q1 = (einw[3] * pp0 + einw[4] * pp1 + einw[5] * pp2 + einb[1]) * QS;
    const float q2 = (einw[6] * pp0 + einw[7] * pp1 + einw[8] * pp2 + einb[2]) * QS;
    const float qt0 = q0 * einw[9]  + q1 * einw[12] + q2 * einw[15];
    const float qt1 = q0 * einw[10] + q1 * einw[13] + q2 * einw[16];
    const float qt2 = q0 * einw[11] + q1 * einw[14] + q2 * einw[17];
    const float ce  = q0 * einb[3] + q1 * einb[4] + q2 * einb[5];
    qa[m] = pk16(qt0, qt1); qb[m] = pk16(qt2, ce);
  }
  const int rho = g + 64 * s;      // owned enc row
  float pr0, pr1, pr2;
  {
    const uint2 prw = sEP[rho];
    const h2 ha = uph(prw.x), hb = uph(prw.y);
    pr0 = (float)ha.x; pr1 = (float)ha.y; pr2 = (float)hb.x;
  }

  // attention: slot s handles j = 4*jj+s; 4 rows share each streamed p_j
  float a0[4] = {0,0,0,0}, a1[4] = {0,0,0,0}, a2[4] = {0,0,0,0},
        dn[4] = {0,0,0,0};
  for (int jj = 0; jj < 64; ++jj) {
    const uint2 pj = sEP[4 * jj + s];
    const h2 pa = uph(pj.x), pb = uph(pj.y);
    const float f0 = (float)pa.x, f1 = (float)pa.y, f2 = (float)pb.x;
#pragma unroll
    for (int m = 0; m < 4; ++m) {
      const float sc = FDOT2(pa, uph(qa[m]), FDOT2(pb, uph(qb[m]), 0.f));
      const float e = EXP2(sc);
      dn[m] += e;
      a0[m] = fmaf(e, f0, a0[m]);
      a1[m] = fmaf(e, f1, a1[m]);
      a2[m] = fmaf(e, f2, a2[m]);
    }
  }
#pragma unroll
  for (int m = 0; m < 4; ++m) { C4(a0[m]); C4(a1[m]); C4(a2[m]); C4(dn[m]); }

  float r0, r1, r2;
  {
    const float myd = sel4(dn[0], dn[1], dn[2], dn[3], s);
    const float mya0 = sel4(a0[0], a0[1], a0[2], a0[3], s);
    const float mya1 = sel4(a1[0], a1[1], a1[2], a1[3], s);
    const float mya2 = sel4(a2[0], a2[1], a2[2], a2[3], s);
    const float rdn = 1.f / myd;
    const float u0 = mya0 * rdn, u1 = mya1 * rdn, u2 = mya2 * rdn;
    const float v0 = einw[18] * u0 + einw[19] * u1 + einw[20] * u2 + einb[6];
    const float v1 = einw[21] * u0 + einw[22] * u1 + einw[23] * u2 + einb[7];
    const float v2 = einw[24] * u0 + einw[25] * u1 + einw[26] * u2 + einb[8];
    r0 = eow[0] * v0 + eow[1] * v1 + eow[2] * v2 + eob[0] + pr0;
    r1 = eow[3] * v0 + eow[4] * v1 + eow[5] * v2 + eob[1] + pr1;
    r2 = eow[6] * v0 + eow[7] * v1 + eow[8] * v2 + eob[2] + pr2;
  }
  float mean, rstd;
  block_stats(r0 + r1 + r2, r0 * r0 + r1 * r1 + r2 * r2, sRed, t, 768.f, mean, rstd);
  const int lie = rho * 3;
  const float x20 = (r0 - mean) * rstd * eln1w[lie + 0] + eln1b[lie + 0];
  const float x21 = (r1 - mean) * rstd * eln1w[lie + 1] + eln1b[lie + 1];
  const float x22 = (r2 - mean) * rstd * eln1w[lie + 2] + eln1b[lie + 2];

  // FFN: slot s handles pairs pp = 4*jj+s over 4 gathered rows
  unsigned xxm[4], xym[4], xzm[4];
  {
    const unsigned xx = pk16(x20, x20), xy = pk16(x21, x21), xz = pk16(x22, x22);
    const int base = lane & ~3;
#pragma unroll
    for (int m = 0; m < 4; ++m) {
      xxm[m] = (unsigned)__shfl((int)xx, base + m, 64);
      xym[m] = (unsigned)__shfl((int)xy, base + m, 64);
      xzm[m] = (unsigned)__shfl((int)xz, base + m, 64);
    }
  }
  float c0[4] = {0,0,0,0}, c1[4] = {0,0,0,0}, c2[4] = {0,0,0,0};
  for (int jj = 0; jj < 64; ++jj) {
    const int pp = 4 * jj + s;
    const uint4 A = sFE[2 * pp];
    const uint4 B = sFE[2 * pp + 1];
    const h2 w1x = uph(A.x), w1y = uph(A.y), w1z = uph(A.z), b1h = uph(A.w);
    const h2 w2x = uph(B.x), w2y = uph(B.y), w2z = uph(B.z);
#pragma unroll
    for (int m = 0; m < 4; ++m) {
      h2 z = w1z * uph(xzm[m]) + b1h;
      z = w1y * uph(xym[m]) + z;
      z = w1x * uph(xxm[m]) + z;
      z = relu2(z);
      c0[m] = FDOT2(z, w2x, c0[m]);
      c1[m] = FDOT2(z, w2y, c1[m]);
      c2[m] = FDOT2(z, w2z, c2[m]);
    }
  }
#pragma unroll
  for (int m = 0; m < 4; ++m) { C4(c0[m]); C4(c1[m]); C4(c2[m]); }

  const float h0 = sel4(c0[0], c0[1], c0[2], c0[3], s) + eb2[0] + x20;
  const float h1 = sel4(c1[0], c1[1], c1[2], c1[3], s) + eb2[1] + x21;
  const float h2v = sel4(c2[0], c2[1], c2[2], c2[3], s) + eb2[2] + x22;
  block_stats(h0 + h1 + h2v, h0 * h0 + h1 * h1 + h2v * h2v, sRed, t, 768.f, mean, rstd);
  {
    const float e0 = (h0 - mean) * rstd * eln2w[lie + 0] + eln2b[lie + 0];
    const float e1 = (h1 - mean) * rstd * eln2w[lie + 1] + eln2b[lie + 1];
    const float e2 = (h2v - mean) * rstd * eln2w[lie + 2] + eln2b[lie + 2];
    sCE[rho] = make_uint2(pk16(e0, e1), pk16(e2, 1.f));
  }
  __syncthreads();

  // ================= DECODER (8-way slots, Q=4 rows) =================
  const int s8 = t & 7;            // dec slot
  const int g8 = t >> 3;           // dec row-group (0..31); rows g8+32m
  const int mo = s8 & 3;           // owned row sub-index (s8>=4 duplicates)
  const int rd = g8 + 32 * mo;     // owned dec row
  const int base8 = lane & ~7;     // octet base lane

  unsigned dqa[4], dqb[4];
#pragma unroll
  for (int m = 0; m < 4; ++m) {
    const uint2 pr = sDP[g8 + 32 * m];
    const h2 ha = uph(pr.x), hb = uph(pr.y);
    const float pp0 = (float)ha.x, pp1 = (float)ha.y, pp2 = (float)hb.x;
    const float q0 = (a1w[0] * pp0 + a1w[1] * pp1 + a1w[2] * pp2 + a1b[0]) * QS;
    const float q1 = (a1w[3] * pp0 + a1w[4] * pp1 + a1w[5] * pp2 + a1b[1]) * QS;
    const float q2 = (a1w[6] * pp0 + a1w[7] * pp1 + a1w[8] * pp2 + a1b[2]) * QS;
    const float qt0 = q0 * a1w[9]  + q1 * a1w[12] + q2 * a1w[15];
    const float qt1 = q0 * a1w[10] + q1 * a1w[13] + q2 * a1w[16];
    const float qt2 = q0 * a1w[11] + q1 * a1w[14] + q2 * a1w[17];
    const float cd  = q0 * a1b[3] + q1 * a1b[4] + q2 * a1b[5];
    dqa[m] = pk16(qt0, qt1); dqb[m] = pk16(qt2, cd);
  }
  float pt0, pt1, pt2;
  {
    const uint2 prw = sDP[rd];
    const h2 ha = uph(prw.x), hb = uph(prw.y);
    pt0 = (float)ha.x; pt1 = (float)ha.y; pt2 = (float)hb.x;
  }

  // self-attn (additive tril(ones) mask -> +LOG2E seed when j<=row)
  float da0[4] = {0,0,0,0}, da1[4] = {0,0,0,0}, da2[4] = {0,0,0,0},
        ddn[4] = {0,0,0,0};
  for (int jj = 0; jj < 16; ++jj) {
    const int j = 8 * jj + s8;
    const uint2 pj = sDP[j];
    const h2 pa = uph(pj.x), pb = uph(pj.y);
    const float f0 = (float)pa.x, f1 = (float)pa.y, f2 = (float)pb.x;
#pragma unroll
    for (int m = 0; m < 4; ++m) {
      const float seed = (j <= g8 + 32 * m) ? LOG2E : 0.f;
      const float sc = FDOT2(pa, uph(dqa[m]), FDOT2(pb, uph(dqb[m]), seed));
      const float e = EXP2(sc);
      ddn[m] += e;
      da0[m] = fmaf(e, f0, da0[m]);
      da1[m] = fmaf(e, f1, da1[m]);
      da2[m] = fmaf(e, f2, da2[m]);
    }
  }
#pragma unroll
  for (int m = 0; m < 4; ++m) { C8(da0[m]); C8(da1[m]); C8(da2[m]); C8(ddn[m]); }
  {
    const float myd = sel4(ddn[0], ddn[1], ddn[2], ddn[3], mo);
    const float rdn = 1.f / myd;
    const float u0 = sel4(da0[0], da0[1], da0[2], da0[3], mo) * rdn;
    const float u1 = sel4(da1[0], da1[1], da1[2], da1[3], mo) * rdn;
    const float u2 = sel4(da2[0], da2[1], da2[2], da2[3], mo) * rdn;
    const float v0 = a1w[18] * u0 + a1w[19] * u1 + a1w[20] * u2 + a1b[6];
    const float v1 = a1w[21] * u0 + a1w[22] * u1 + a1w[23] * u2 + a1b[7];
    const float v2 = a1w[24] * u0 + a1w[25] * u1 + a1w[26] * u2 + a1b[8];
    r0 = a1ow[0] * v0 + a1ow[1] * v1 + a1ow[2] * v2 + a1ob[0] + pt0;
    r1 = a1ow[3] * v0 + a1ow[4] * v1 + a1ow[5] * v2 + a1ob[1] + pt1;
    r2 = a1ow[6] * v0 + a1ow[7] * v1 + a1ow[8] * v2 + a1ob[2] + pt2;
  }
  const int dc = (s8 < 4) ? 1 : 0;   // unique dec-row coverage gate
  block_stats(dc ? r0 + r1 + r2 : 0.f,
              dc ? r0 * r0 + r1 * r1 + r2 * r2 : 0.f, sRed, t, 384.f, mean, rstd);
  const int lid = rd * 3;
  const float dl1w0 = dln1w[lid + 0], dl1w1 = dln1w[lid + 1], dl1w2 = dln1w[lid + 2];
  const float dl1b0 = dln1b[lid + 0], dl1b1 = dln1b[lid + 1], dl1b2 = dln1b[lid + 2];
  const float x2d0 = (r0 - mean) * rstd * dl1w0 + dl1b0;
  const float x2d1 = (r1 - mean) * rstd * dl1w1 + dl1b1;
  const float x2d2 = (r2 - mean) * rstd * dl1w2 + dl1b2;

  // cross-attn queries for the 4 octet rows (owners live at base8+0..3)
  unsigned cqa[4], cqb[4];
#pragma unroll
  for (int m = 0; m < 4; ++m) {
    const float y0 = __shfl(x2d0, base8 + m, 64);
    const float y1 = __shfl(x2d1, base8 + m, 64);
    const float y2 = __shfl(x2d2, base8 + m, 64);
    const float q0 = (a2w[0] * y0 + a2w[1] * y1 + a2w[2] * y2 + a2b[0]) * QS;
    const float q1 = (a2w[3] * y0 + a2w[4] * y1 + a2w[5] * y2 + a2b[1]) * QS;
    const float q2 = (a2w[6] * y0 + a2w[7] * y1 + a2w[8] * y2 + a2b[2]) * QS;
    const float qt0 = q0 * a2w[9]  + q1 * a2w[12] + q2 * a2w[15];
    const float qt1 = q0 * a2w[10] + q1 * a2w[13] + q2 * a2w[16];
    const float qt2 = q0 * a2w[11] + q1 * a2w[14] + q2 * a2w[17];
    const float cc  = q0 * a2b[3] + q1 * a2b[4] + q2 * a2b[5];
    cqa[m] = pk16(qt0, qt1); cqb[m] = pk16(qt2, cc);
  }
#pragma unroll
  for (int m = 0; m < 4; ++m) { da0[m] = 0.f; da1[m] = 0.f; da2[m] = 0.f; ddn[m] = 0.f; }
  for (int jj = 0; jj < 32; ++jj) {
    const uint2 pj = sCE[8 * jj + s8];
    const h2 pa = uph(pj.x), pb = uph(pj.y);
    const float f0 = (float)pa.x, f1 = (float)pa.y, f2 = (float)pb.x;
#pragma unroll
    for (int m = 0; m < 4; ++m) {
      const float sc = FDOT2(pa, uph(cqa[m]), FDOT2(pb, uph(cqb[m]), 0.f));
      const float e = EXP2(sc);
      ddn[m] += e;
      da0[m] = fmaf(e, f0, da0[m]);
      da1[m] = fmaf(e, f1, da1[m]);
      da2[m] = fmaf(e, f2, da2[m]);
    }
  }
#pragma unroll
  for (int m = 0; m < 4; ++m) { C8(da0[m]); C8(da1[m]); C8(da2[m]); C8(ddn[m]); }
  {
    const float myd = sel4(ddn[0], ddn[1], ddn[2], ddn[3], mo);
    const float rdn = 1.f / myd;
    const float u0 = sel4(da0[0], da0[1], da0[2], da0[3], mo) * rdn;
    const float u1 = sel4(da1[0], da1[1], da1[2], da1[3], mo) * rdn;
    const float u2 = sel4(da2[0], da2[1], da2[2], da2[3], mo) * rdn;
    const float v0 = a2w[18] * u0 + a2w[19] * u1 + a2w[20] * u2 + a2b[6];
    const float v1 = a2w[21] * u0 + a2w[22] * u1 + a2w[23] * u2 + a2b[7];
    const float v2 = a2w[24] * u0 + a2w[25] * u1 + a2w[26] * u2 + a2b[8];
    r0 = a2ow[0] * v0 + a2ow[1] * v1 + a2ow[2] * v2 + a2ob[0] + x2d0;
    r1 = a2ow[3] * v0 + a2ow[4] * v1 + a2ow[5] * v2 + a2ob[1] + x2d1;
    r2 = a2ow[6] * v0 + a2ow[7] * v1 + a2ow[8] * v2 + a2ob[2] + x2d2;
  }
  block_stats(dc ? r0 + r1 + r2 : 0.f,
              dc ? r0 * r0 + r1 * r1 + r2 * r2 : 0.f, sRed, t, 384.f, mean, rstd);
  const float x30 = (r0 - mean) * rstd * dl1w0 + dl1b0;   // dec_ln1 AGAIN
  const float x31 = (r1 - mean) * rstd * dl1w1 + dl1b1;
  const float x32 = (r2 - mean) * rstd * dl1w2 + dl1b2;

  // dec FFN: all 4 octet rows' x3 as h2 broadcasts
  unsigned x3x[4], x3y[4], x3z[4];
  {
    const unsigned xx = pk16(x30, x30), xy = pk16(x31, x31), xz = pk16(x32, x32);
#pragma unroll
    for (int m = 0; m < 4; ++m) {
      x3x[m] = (unsigned)__shfl((int)xx, base8 + m, 64);
      x3y[m] = (unsigned)__shfl((int)xy, base8 + m, 64);
      x3z[m] = (unsigned)__shfl((int)xz, base8 + m, 64);
    }
  }
  float e0[4] = {0,0,0,0}, e1[4] = {0,0,0,0}, e2[4] = {0,0,0,0};
  for (int jj = 0; jj < 32; ++jj) {
    const int pp = 8 * jj + s8;
    const uint4 A = sFD[2 * pp];
    const uint4 B = sFD[2 * pp + 1];
    const h2 w1x = uph(A.x), w1y = uph(A.y), w1z = uph(A.z), b1h = uph(A.w);
    const h2 w2x = uph(B.x), w2y = uph(B.y), w2z = uph(B.z);
#pragma unroll
    for (int m = 0; m < 4; ++m) {
      h2 z = w1z * uph(x3z[m]) + b1h;
      z = w1y * uph(x3y[m]) + z;
      z = w1x * uph(x3x[m]) + z;
      z = relu2(z);
      e0[m] = FDOT2(z, w2x, e0[m]);
      e1[m] = FDOT2(z, w2y, e1[m]);
      e2[m] = FDOT2(z, w2z, e2[m]);
    }
  }
#pragma unroll
  for (int m = 0; m < 4; ++m) { C8(e0[m]); C8(e1[m]); C8(e2[m]); }

  const float f0 = sel4(e0[0], e0[1], e0[2], e0[3], mo) + db2[0] + x30;
  const float f1 = sel4(e1[0], e1[1], e1[2], e1[3], mo) + db2[1] + x31;
  const float f2 = sel4(e2[0], e2[1], e2[2], e2[3], mo) + db2[2] + x32;
  block_stats(dc ? f0 + f1 + f2 : 0.f,
              dc ? f0 * f0 + f1 * f1 + f2 * f2 : 0.f, sRed, t, 384.f, mean, rstd);
  if (s8 < 4) {
    float* op = out + ((size_t)b * SPRQ + rd) * 3;
    op[0] = (f0 - mean) * rstd * dln3w[lid + 0] + dln3b[lid + 0];
    op[1] = (f1 - mean) * rstd * dln3w[lid + 1] + dln3b[lid + 1];
    op[2] = (f2 - mean) * rstd * dln3w[lid + 2] + dln3b[lid + 2];
  }
}

extern "C" void kernel_launch(void* const* d_in, const int* in_sizes, int n_in,
                              void* d_out, int out_size, void* d_ws, size_t ws_size,
                              hipStream_t stream) {
  (void)in_sizes; (void)n_in; (void)out_size; (void)ws_size;
  float* ws = (float*)d_ws;
  uint4* fE = (uint4*)ws;                    // 8 KB
  uint4* fD = (uint4*)(ws + 2048);           // 8 KB
  float4* pe = (float4*)(ws + 4096);         // 4 KB

  pack_tabs<<<1, 256, 0, stream>>>(
      (const float*)d_in[8],  (const float*)d_in[9],  (const float*)d_in[10],
      (const float*)d_in[24], (const float*)d_in[25], (const float*)d_in[26],
      fE, fD, pe);

  fused_fwd<<<NB, 256, 0, stream>>>(
      (const float*)d_in[0],  (const float*)d_in[1],
      (const float*)d_in[2],  (const float*)d_in[3],
      (const float*)d_in[4],  (const float*)d_in[5],
      (const float*)d_in[6],  (const float*)d_in[7],
      (const float*)d_in[11],
      (const float*)d_in[12], (const float*)d_in[13],
      (const float*)d_in[14], (const float*)d_in[15],
      (const float*)d_in[16], (const float*)d_in[17],
      (const float*)d_in[18], (const float*)d_in[19],
      (const float*)d_in[20], (const float*)d_in[21],
      (const float*)d_in[22], (const float*)d_in[23],
      (const float*)d_in[27],
      (const float*)d_in[28], (const float*)d_in[29],
      fE, fD, pe,
      (float*)d_out);
}

// Round 13
// 178.602 us; speedup vs baseline: 1.1470x; 1.1470x over previous
//
#include <hip/hip_runtime.h>

#define NB   1024
#define SINQ 256
#define SPRQ 128
#define HIDQ 512

// pos_enc: emb[:, :3] = sin(pos * inv_freq[c]); inv_freq[c] = 10000^(-2c/256)
#define PEF1  0.93057207f
#define PEF2  0.86596438f
#define LOG2E 1.44269504089f
// q pre-scale: 1/sqrt(3) * log2(e)
#define QS    0.83298066476f

typedef _Float16 h2 __attribute__((ext_vector_type(2)));

#if defined(__has_builtin) && __has_builtin(__builtin_amdgcn_exp2f)
#define EXP2(x) __builtin_amdgcn_exp2f(x)
#else
#define EXP2(x) exp2f(x)
#endif

#if defined(__has_builtin) && __has_builtin(__builtin_amdgcn_fdot2)
#define FDOT2(a, b, c) __builtin_amdgcn_fdot2((a), (b), (c), false)
#else
__device__ __forceinline__ float fdot2_sw(h2 a, h2 b, float c) {
  return fmaf((float)a.x, (float)b.x, fmaf((float)a.y, (float)b.y, c));
}
#define FDOT2(a, b, c) fdot2_sw((a), (b), (c))
#endif

__device__ __forceinline__ unsigned pk16(float a, float b) {
  h2 v; v.x = (_Float16)a; v.y = (_Float16)b;
  return __builtin_bit_cast(unsigned, v);
}
__device__ __forceinline__ h2 uph(unsigned u) { return __builtin_bit_cast(h2, u); }

__device__ __forceinline__ h2 relu2(h2 z) {
#if defined(__has_builtin) && __has_builtin(__builtin_elementwise_max)
  h2 zz; zz.x = (_Float16)0.f; zz.y = (_Float16)0.f;
  return __builtin_elementwise_max(z, zz);
#else
  z.x = z.x > (_Float16)0.f ? z.x : (_Float16)0.f;
  z.y = z.y > (_Float16)0.f ? z.y : (_Float16)0.f;
  return z;
#endif
}

// register-only selects (v_cndmask chains) -- NEVER index private arrays
// with a runtime value: that demotes them to scratch (HBM!).
// Spill-cliff ledger (this kernel, 256-thr blocks): VGPR 44 = spill-free
// (R7/R11, ~70.8 us fused); ~64 live = 100-430 MB scratch traffic
// (R8/R9/R10/R12). Keep enc Q=4 / dec Q=2; do NOT widen per-thread state.
__device__ __forceinline__ float sel4(float a, float b, float c, float d, int s) {
  float r = a;
  r = (s == 1) ? b : r;
  r = (s == 2) ? c : r;
  r = (s == 3) ? d : r;
  return r;
}
__device__ __forceinline__ float sel2(float a, float b, int s) {
  return s ? b : a;
}

// xor-combine over the 4 slot lanes of a quad
#define C4(v) { v += __shfl_xor((v), 1, 64); v += __shfl_xor((v), 2, 64); }

// Block-wide (256 thr) mean/rstd over nelem values.
__device__ __forceinline__ void block_stats(float s1, float s2, float* sRed,
                                            int tid, float nelem,
                                            float& mean, float& rstd) {
#pragma unroll
  for (int off = 32; off > 0; off >>= 1) {
    s1 += __shfl_xor(s1, off, 64);
    s2 += __shfl_xor(s2, off, 64);
  }
  __syncthreads();
  if ((tid & 63) == 0) {
    sRed[((tid >> 6) << 1) + 0] = s1;
    sRed[((tid >> 6) << 1) + 1] = s2;
  }
  __syncthreads();
  float t1 = sRed[0] + sRed[2] + sRed[4] + sRed[6];
  float t2 = sRed[1] + sRed[3] + sRed[5] + sRed[7];
  mean = t1 / nelem;
  rstd = rsqrtf(t2 / nelem - mean * mean + 1e-5f);
}

// Pack f16 FFN pair-records and the sin() table.
__global__ __launch_bounds__(256) void pack_tabs(
    const float* __restrict__ ew1, const float* __restrict__ eb1,
    const float* __restrict__ ew2,
    const float* __restrict__ dw1, const float* __restrict__ db1,
    const float* __restrict__ dw2,
    uint4* __restrict__ fE, uint4* __restrict__ fD, float4* __restrict__ pe)
{
  const int t = threadIdx.x;        // pair index, 0..255
  const int k0 = 2 * t, k1 = 2 * t + 1;
  fE[2 * t] = make_uint4(pk16(ew1[3 * k0], ew1[3 * k1]),
                         pk16(ew1[3 * k0 + 1], ew1[3 * k1 + 1]),
                         pk16(ew1[3 * k0 + 2], ew1[3 * k1 + 2]),
                         pk16(eb1[k0], eb1[k1]));
  fE[2 * t + 1] = make_uint4(pk16(ew2[k0], ew2[k1]),
                             pk16(ew2[HIDQ + k0], ew2[HIDQ + k1]),
                             pk16(ew2[2 * HIDQ + k0], ew2[2 * HIDQ + k1]), 0u);
  fD[2 * t] = make_uint4(pk16(dw1[3 * k0], dw1[3 * k1]),
                         pk16(dw1[3 * k0 + 1], dw1[3 * k1 + 1]),
                         pk16(dw1[3 * k0 + 2], dw1[3 * k1 + 2]),
                         pk16(db1[k0], db1[k1]));
  fD[2 * t + 1] = make_uint4(pk16(dw2[k0], dw2[k1]),
                             pk16(dw2[HIDQ + k0], dw2[HIDQ + k1]),
                             pk16(dw2[2 * HIDQ + k0], dw2[2 * HIDQ + k1]), 0u);
  const float p = (float)t;
  pe[t] = make_float4(sinf(p), sinf(p * PEF1), sinf(p * PEF2), 0.f);
}

// One 256-thr block per batch element. 4-way slot-split (s = t&3) over j/k,
// Q=4 rows/thread (enc) and Q=2 (dec); combines via shfl_xor.
__global__ __launch_bounds__(256, 4) void fused_fwd(
    const float* __restrict__ X, const float* __restrict__ T,
    const float* __restrict__ einw, const float* __restrict__ einb,
    const float* __restrict__ eow,  const float* __restrict__ eob,
    const float* __restrict__ eln1w, const float* __restrict__ eln1b,
    const float* __restrict__ eb2,
    const float* __restrict__ eln2w, const float* __restrict__ eln2b,
    const float* __restrict__ a1w, const float* __restrict__ a1b,
    const float* __restrict__ a1ow, const float* __restrict__ a1ob,
    const float* __restrict__ dln1w, const float* __restrict__ dln1b,
    const float* __restrict__ a2w, const float* __restrict__ a2b,
    const float* __restrict__ a2ow, const float* __restrict__ a2ob,
    const float* __restrict__ db2,
    const float* __restrict__ dln3w, const float* __restrict__ dln3b,
    const uint4* __restrict__ fE, const uint4* __restrict__ fD,
    const float4* __restrict__ pe,
    float* __restrict__ out)
{
  __shared__ uint4 sFE[2 * 256];   // 8 KB enc FFN pair-records
  __shared__ uint4 sFD[2 * 256];   // 8 KB dec FFN pair-records
  __shared__ uint2 sEP[SINQ];      // 2 KB f16 p_X rows {(p0,p1),(p2,1)}
  __shared__ uint2 sDP[SPRQ];      // 1 KB f16 p_T rows
  __shared__ uint2 sCE[SINQ];      // 2 KB f16 enc_out rows
  __shared__ float sRed[8];

  const int b = blockIdx.x;
  const int t = threadIdx.x;
  const int lane = t & 63;
  const int s = t & 3;             // slot
  const int g = t >> 2;            // enc row-group (0..63)

  // ---- stage tables + p-rows
  sFE[t] = fE[t]; sFE[t + 256] = fE[t + 256];
  sFD[t] = fD[t]; sFD[t + 256] = fD[t + 256];
  {
    const float4 peT = pe[t];
    const float* xr = X + (size_t)b * SINQ * 3 + 3 * t;
    sEP[t] = make_uint2(pk16(xr[0] + peT.x, xr[1] + peT.y),
                        pk16(xr[2] + peT.z, 1.f));
    if (t < SPRQ) {
      const float* tr = T + (size_t)b * SPRQ * 3 + 3 * t;
      sDP[t] = make_uint2(pk16(tr[0] + peT.x, tr[1] + peT.y),
                          pk16(tr[2] + peT.z, 1.f));
    }
  }
  __syncthreads();

  // ================= ENCODER =================
  unsigned qa[4], qb[4];
#pragma unroll
  for (int m = 0; m < 4; ++m) {
    const uint2 pr = sEP[g + 64 * m];
    const h2 ha = uph(pr.x), hb = uph(pr.y);
    const float pp0 = (float)ha.x, pp1 = (float)ha.y, pp2 = (float)hb.x;
    const float q0 = (einw[0] * pp0 + einw[1] * pp1 + einw[2] * pp2 + einb[0]) * QS;
    const float q1 = (einw[3] * pp0 + einw[4] * pp1 + einw[5] * pp2 + einb[1]) * QS;
    const float q2 = (einw[6] * pp0 + einw[7] * pp1 + einw[8] * pp2 + einb[2]) * QS;
    const float qt0 = q0 * einw[9]  + q1 * einw[12] + q2 * einw[15];
    const float qt1 = q0 * einw[10] + q1 * einw[13] + q2 * einw[16];
    const float qt2 = q0 * einw[11] + q1 * einw[14] + q2 * einw[17];
    const float ce  = q0 * einb[3] + q1 * einb[4] + q2 * einb[5];
    qa[m] = pk16(qt0, qt1); qb[m] = pk16(qt2, ce);
  }
  // own row's p via direct LDS broadcast (no dynamic reg indexing)
  const int rho = g + 64 * s;
  float pr0, pr1, pr2;
  {
    const uint2 prw = sEP[rho];
    const h2 ha = uph(prw.x), hb = uph(prw.y);
    pr0 = (float)ha.x; pr1 = (float)ha.y; pr2 = (float)hb.x;
  }

  // attention: slot s handles j = 4*jj+s; 4 rows share each streamed p_j
  float a0[4] = {0,0,0,0}, a1[4] = {0,0,0,0}, a2[4] = {0,0,0,0},
        dn[4] = {0,0,0,0};
  for (int jj = 0; jj < 64; ++jj) {
    const uint2 pj = sEP[4 * jj + s];
    const h2 pa = uph(pj.x), pb = uph(pj.y);
    const float f0 = (float)pa.x, f1 = (float)pa.y, f2 = (float)pb.x;
#pragma unroll
    for (int m = 0; m < 4; ++m) {
      const float sc = FDOT2(pa, uph(qa[m]), FDOT2(pb, uph(qb[m]), 0.f));
      const float e = EXP2(sc);
      dn[m] += e;
      a0[m] = fmaf(e, f0, a0[m]);
      a1[m] = fmaf(e, f1, a1[m]);
      a2[m] = fmaf(e, f2, a2[m]);
    }
  }
#pragma unroll
  for (int m = 0; m < 4; ++m) { C4(a0[m]); C4(a1[m]); C4(a2[m]); C4(dn[m]); }

  float r0, r1, r2;
  {
    const float myd = sel4(dn[0], dn[1], dn[2], dn[3], s);
    const float mya0 = sel4(a0[0], a0[1], a0[2], a0[3], s);
    const float mya1 = sel4(a1[0], a1[1], a1[2], a1[3], s);
    const float mya2 = sel4(a2[0], a2[1], a2[2], a2[3], s);
    const float rdn = 1.f / myd;
    const float u0 = mya0 * rdn, u1 = mya1 * rdn, u2 = mya2 * rdn;
    const float v0 = einw[18] * u0 + einw[19] * u1 + einw[20] * u2 + einb[6];
    const float v1 = einw[21] * u0 + einw[22] * u1 + einw[23] * u2 + einb[7];
    const float v2 = einw[24] * u0 + einw[25] * u1 + einw[26] * u2 + einb[8];
    r0 = eow[0] * v0 + eow[1] * v1 + eow[2] * v2 + eob[0] + pr0;
    r1 = eow[3] * v0 + eow[4] * v1 + eow[5] * v2 + eob[1] + pr1;
    r2 = eow[6] * v0 + eow[7] * v1 + eow[8] * v2 + eob[2] + pr2;
  }
  float mean, rstd;
  block_stats(r0 + r1 + r2, r0 * r0 + r1 * r1 + r2 * r2, sRed, t, 768.f, mean, rstd);
  const int lie = rho * 3;
  const float x20 = (r0 - mean) * rstd * eln1w[lie + 0] + eln1b[lie + 0];
  const float x21 = (r1 - mean) * rstd * eln1w[lie + 1] + eln1b[lie + 1];
  const float x22 = (r2 - mean) * rstd * eln1w[lie + 2] + eln1b[lie + 2];

  // FFN: slot s handles pairs pp = 4*jj+s over 4 gathered rows
  unsigned xxm[4], xym[4], xzm[4];
  {
    const unsigned xx = pk16(x20, x20), xy = pk16(x21, x21), xz = pk16(x22, x22);
    const int base = lane & ~3;
#pragma unroll
    for (int m = 0; m < 4; ++m) {
      xxm[m] = (unsigned)__shfl((int)xx, base + m, 64);
      xym[m] = (unsigned)__shfl((int)xy, base + m, 64);
      xzm[m] = (unsigned)__shfl((int)xz, base + m, 64);
    }
  }
  float c0[4] = {0,0,0,0}, c1[4] = {0,0,0,0}, c2[4] = {0,0,0,0};
  for (int jj = 0; jj < 64; ++jj) {
    const int pp = 4 * jj + s;
    const uint4 A = sFE[2 * pp];
    const uint4 B = sFE[2 * pp + 1];
    const h2 w1x = uph(A.x), w1y = uph(A.y), w1z = uph(A.z), b1h = uph(A.w);
    const h2 w2x = uph(B.x), w2y = uph(B.y), w2z = uph(B.z);
#pragma unroll
    for (int m = 0; m < 4; ++m) {
      h2 z = w1z * uph(xzm[m]) + b1h;
      z = w1y * uph(xym[m]) + z;
      z = w1x * uph(xxm[m]) + z;
      z = relu2(z);
      c0[m] = FDOT2(z, w2x, c0[m]);
      c1[m] = FDOT2(z, w2y, c1[m]);
      c2[m] = FDOT2(z, w2z, c2[m]);
    }
  }
#pragma unroll
  for (int m = 0; m < 4; ++m) { C4(c0[m]); C4(c1[m]); C4(c2[m]); }

  const float h0 = sel4(c0[0], c0[1], c0[2], c0[3], s) + eb2[0] + x20;
  const float h1 = sel4(c1[0], c1[1], c1[2], c1[3], s) + eb2[1] + x21;
  const float h2v = sel4(c2[0], c2[1], c2[2], c2[3], s) + eb2[2] + x22;
  block_stats(h0 + h1 + h2v, h0 * h0 + h1 * h1 + h2v * h2v, sRed, t, 768.f, mean, rstd);
  {
    const float e0 = (h0 - mean) * rstd * eln2w[lie + 0] + eln2b[lie + 0];
    const float e1 = (h1 - mean) * rstd * eln2w[lie + 1] + eln2b[lie + 1];
    const float e2 = (h2v - mean) * rstd * eln2w[lie + 2] + eln2b[lie + 2];
    sCE[rho] = make_uint2(pk16(e0, e1), pk16(e2, 1.f));
  }
  __syncthreads();

  // ================= DECODER =================
  const int ms = s & 1;            // assigned row: ra = g + 64*ms
  const int ra = g + 64 * ms;

  unsigned dqa[2], dqb[2];
#pragma unroll
  for (int m = 0; m < 2; ++m) {
    const uint2 pr = sDP[g + 64 * m];
    const h2 ha = uph(pr.x), hb = uph(pr.y);
    const float pp0 = (float)ha.x, pp1 = (float)ha.y, pp2 = (float)hb.x;
    const float q0 = (a1w[0] * pp0 + a1w[1] * pp1 + a1w[2] * pp2 + a1b[0]) * QS;
    const float q1 = (a1w[3] * pp0 + a1w[4] * pp1 + a1w[5] * pp2 + a1b[1]) * QS;
    const float q2 = (a1w[6] * pp0 + a1w[7] * pp1 + a1w[8] * pp2 + a1b[2]) * QS;
    const float qt0 = q0 * a1w[9]  + q1 * a1w[12] + q2 * a1w[15];
    const float qt1 = q0 * a1w[10] + q1 * a1w[13] + q2 * a1w[16];
    const float qt2 = q0 * a1w[11] + q1 * a1w[14] + q2 * a1w[17];
    const float cd  = q0 * a1b[3] + q1 * a1b[4] + q2 * a1b[5];
    dqa[m] = pk16(qt0, qt1); dqb[m] = pk16(qt2, cd);
  }
  float pt0, pt1, pt2;
  {
    const uint2 prw = sDP[ra];
    const h2 ha = uph(prw.x), hb = uph(prw.y);
    pt0 = (float)ha.x; pt1 = (float)ha.y; pt2 = (float)hb.x;
  }

  // self-attn (additive tril(ones) mask -> +LOG2E seed when j<=row)
  float da0[2] = {0,0}, da1[2] = {0,0}, da2[2] = {0,0}, ddn[2] = {0,0};
  for (int jj = 0; jj < 32; ++jj) {
    const int j = 4 * jj + s;
    const uint2 pj = sDP[j];
    const h2 pa = uph(pj.x), pb = uph(pj.y);
    const float f0 = (float)pa.x, f1 = (float)pa.y, f2 = (float)pb.x;
#pragma unroll
    for (int m = 0; m < 2; ++m) {
      const float seed = (j <= g + 64 * m) ? LOG2E : 0.f;
      const float sc = FDOT2(pa, uph(dqa[m]), FDOT2(pb, uph(dqb[m]), seed));
      const float e = EXP2(sc);
      ddn[m] += e;
      da0[m] = fmaf(e, f0, da0[m]);
      da1[m] = fmaf(e, f1, da1[m]);
      da2[m] = fmaf(e, f2, da2[m]);
    }
  }
#pragma unroll
  for (int m = 0; m < 2; ++m) { C4(da0[m]); C4(da1[m]); C4(da2[m]); C4(ddn[m]); }
  {
    const float myd = sel2(ddn[0], ddn[1], ms);
    const float rdn = 1.f / myd;
    const float u0 = sel2(da0[0], da0[1], ms) * rdn;
    const float u1 = sel2(da1[0], da1[1], ms) * rdn;
    const float u2 = sel2(da2[0], da2[1], ms) * rdn;
    const float v0 = a1w[18] * u0 + a1w[19] * u1 + a1w[20] * u2 + a1b[6];
    const float v1 = a1w[21] * u0 + a1w[22] * u1 + a1w[23] * u2 + a1b[7];
    const float v2 = a1w[24] * u0 + a1w[25] * u1 + a1w[26] * u2 + a1b[8];
    r0 = a1ow[0] * v0 + a1ow[1] * v1 + a1ow[2] * v2 + a1ob[0] + pt0;
    r1 = a1ow[3] * v0 + a1ow[4] * v1 + a1ow[5] * v2 + a1ob[1] + pt1;
    r2 = a1ow[6] * v0 + a1ow[7] * v1 + a1ow[8] * v2 + a1ob[2] + pt2;
  }
  const int contrib = (s < 2) ? 1 : 0;
  block_stats(contrib ? r0 + r1 + r2 : 0.f,
              contrib ? r0 * r0 + r1 * r1 + r2 * r2 : 0.f, sRed, t, 384.f, mean, rstd);
  const int lid = ra * 3;
  const float dl1w0 = dln1w[lid + 0], dl1w1 = dln1w[lid + 1], dl1w2 = dln1w[lid + 2];
  const float dl1b0 = dln1b[lid + 0], dl1b1 = dln1b[lid + 1], dl1b2 = dln1b[lid + 2];
  const float x2d0 = (r0 - mean) * rstd * dl1w0 + dl1b0;
  const float x2d1 = (r1 - mean) * rstd * dl1w1 + dl1b1;
  const float x2d2 = (r2 - mean) * rstd * dl1w2 + dl1b2;

  // cross-attn queries for BOTH rows (shfl + selects; no dynamic stores)
  unsigned cqa[2], cqb[2];
  {
    const int oth = (lane & ~3) + (ms ^ 1);
    const float ox0 = __shfl(x2d0, oth, 64);
    const float ox1 = __shfl(x2d1, oth, 64);
    const float ox2 = __shfl(x2d2, oth, 64);
    const float y00 = ms ? ox0 : x2d0;   // row m=0
    const float y01 = ms ? ox1 : x2d1;
    const float y02 = ms ? ox2 : x2d2;
    const float y10 = ms ? x2d0 : ox0;   // row m=1
    const float y11 = ms ? x2d1 : ox1;
    const float y12 = ms ? x2d2 : ox2;
#pragma unroll
    for (int m = 0; m < 2; ++m) {
      const float y0 = m ? y10 : y00, y1 = m ? y11 : y01, y2 = m ? y12 : y02;
      const float q0 = (a2w[0] * y0 + a2w[1] * y1 + a2w[2] * y2 + a2b[0]) * QS;
      const float q1 = (a2w[3] * y0 + a2w[4] * y1 + a2w[5] * y2 + a2b[1]) * QS;
      const float q2 = (a2w[6] * y0 + a2w[7] * y1 + a2w[8] * y2 + a2b[2]) * QS;
      const float qt0 = q0 * a2w[9]  + q1 * a2w[12] + q2 * a2w[15];
      const float qt1 = q0 * a2w[10] + q1 * a2w[13] + q2 * a2w[16];
      const float qt2 = q0 * a2w[11] + q1 * a2w[14] + q2 * a2w[17];
      const float cc  = q0 * a2b[3] + q1 * a2b[4] + q2 * a2b[5];
      cqa[m] = pk16(qt0, qt1); cqb[m] = pk16(qt2, cc);
    }
  }
  da0[0] = da0[1] = da1[0] = da1[1] = da2[0] = da2[1] = ddn[0] = ddn[1] = 0.f;
  for (int jj = 0; jj < 64; ++jj) {
    const uint2 pj = sCE[4 * jj + s];
    const h2 pa = uph(pj.x), pb = uph(pj.y);
    const float f0 = (float)pa.x, f1 = (float)pa.y, f2 = (float)pb.x;
#pragma unroll
    for (int m = 0; m < 2; ++m) {
      const float sc = FDOT2(pa, uph(cqa[m]), FDOT2(pb, uph(cqb[m]), 0.f));
      const float e = EXP2(sc);
      ddn[m] += e;
      da0[m] = fmaf(e, f0, da0[m]);
      da1[m] = fmaf(e, f1, da1[m]);
      da2[m] = fmaf(e, f2, da2[m]);
    }
  }
#pragma unroll
  for (int m = 0; m < 2; ++m) { C4(da0[m]); C4(da1[m]); C4(da2[m]); C4(ddn[m]); }
  {
    const float myd = sel2(ddn[0], ddn[1], ms);
    const float rdn = 1.f / myd;
    const float u0 = sel2(da0[0], da0[1], ms) * rdn;
    const float u1 = sel2(da1[0], da1[1], ms) * rdn;
    const float u2 = sel2(da2[0], da2[1], ms) * rdn;
    const float v0 = a2w[18] * u0 + a2w[19] * u1 + a2w[20] * u2 + a2b[6];
    const float v1 = a2w[21] * u0 + a2w[22] * u1 + a2w[23] * u2 + a2b[7];
    const float v2 = a2w[24] * u0 + a2w[25] * u1 + a2w[26] * u2 + a2b[8];
    r0 = a2ow[0] * v0 + a2ow[1] * v1 + a2ow[2] * v2 + a2ob[0] + x2d0;
    r1 = a2ow[3] * v0 + a2ow[4] * v1 + a2ow[5] * v2 + a2ob[1] + x2d1;
    r2 = a2ow[6] * v0 + a2ow[7] * v1 + a2ow[8] * v2 + a2ob[2] + x2d2;
  }
  block_stats(contrib ? r0 + r1 + r2 : 0.f,
              contrib ? r0 * r0 + r1 * r1 + r2 * r2 : 0.f, sRed, t, 384.f, mean, rstd);
  const float x30 = (r0 - mean) * rstd * dl1w0 + dl1b0;   // dec_ln1 AGAIN
  const float x31 = (r1 - mean) * rstd * dl1w1 + dl1b1;
  const float x32 = (r2 - mean) * rstd * dl1w2 + dl1b2;

  // dec FFN: both rows' x3 as h2 broadcasts (shfl + selects)
  unsigned x3x0, x3y0, x3z0, x3x1, x3y1, x3z1;
  {
    const unsigned xx = pk16(x30, x30), xy = pk16(x31, x31), xz = pk16(x32, x32);
    const int oth = (lane & ~3) + (ms ^ 1);
    const unsigned oxx = (unsigned)__shfl((int)xx, oth, 64);
    const unsigned oxy = (unsigned)__shfl((int)xy, oth, 64);
    const unsigned oxz = (unsigned)__shfl((int)xz, oth, 64);
    x3x0 = ms ? oxx : xx; x3y0 = ms ? oxy : xy; x3z0 = ms ? oxz : xz;
    x3x1 = ms ? xx : oxx; x3y1 = ms ? xy : oxy; x3z1 = ms ? xz : oxz;
  }
  float e0[2] = {0,0}, e1[2] = {0,0}, e2[2] = {0,0};
  for (int jj = 0; jj < 64; ++jj) {
    const int pp = 4 * jj + s;
    const uint4 A = sFD[2 * pp];
    const uint4 B = sFD[2 * pp + 1];
    const h2 w1x = uph(A.x), w1y = uph(A.y), w1z = uph(A.z), b1h = uph(A.w);
    const h2 w2x = uph(B.x), w2y = uph(B.y), w2z = uph(B.z);
#pragma unroll
    for (int m = 0; m < 2; ++m) {
      h2 z = w1z * uph(m ? x3z1 : x3z0) + b1h;
      z = w1y * uph(m ? x3y1 : x3y0) + z;
      z = w1x * uph(m ? x3x1 : x3x0) + z;
      z = relu2(z);
      e0[m] = FDOT2(z, w2x, e0[m]);
      e1[m] = FDOT2(z, w2y, e1[m]);
      e2[m] = FDOT2(z, w2z, e2[m]);
    }
  }
#pragma unroll
  for (int m = 0; m < 2; ++m) { C4(e0[m]); C4(e1[m]); C4(e2[m]); }

  const float f0 = sel2(e0[0], e0[1], ms) + db2[0] + x30;
  const float f1 = sel2(e1[0], e1[1], ms) + db2[1] + x31;
  const float f2 = sel2(e2[0], e2[1], ms) + db2[2] + x32;
  block_stats(contrib ? f0 + f1 + f2 : 0.f,
              contrib ? f0 * f0 + f1 * f1 + f2 * f2 : 0.f, sRed, t, 384.f, mean, rstd);
  if (s < 2) {
    float* op = out + ((size_t)b * SPRQ + ra) * 3;
    op[0] = (f0 - mean) * rstd * dln3w[lid + 0] + dln3b[lid + 0];
    op[1] = (f1 - mean) * rstd * dln3w[lid + 1] + dln3b[lid + 1];
    op[2] = (f2 - mean) * rstd * dln3w[lid + 2] + dln3b[lid + 2];
  }
}

extern "C" void kernel_launch(void* const* d_in, const int* in_sizes, int n_in,
                              void* d_out, int out_size, void* d_ws, size_t ws_size,
                              hipStream_t stream) {
  (void)in_sizes; (void)n_in; (void)out_size; (void)ws_size;
  float* ws = (float*)d_ws;
  uint4* fE = (uint4*)ws;                    // 8 KB
  uint4* fD = (uint4*)(ws + 2048);           // 8 KB
  float4* pe = (float4*)(ws + 4096);         // 4 KB

  pack_tabs<<<1, 256, 0, stream>>>(
      (const float*)d_in[8],  (const float*)d_in[9],  (const float*)d_in[10],
      (const float*)d_in[24], (const float*)d_in[25], (const float*)d_in[26],
      fE, fD, pe);

  fused_fwd<<<NB, 256, 0, stream>>>(
      (const float*)d_in[0],  (const float*)d_in[1],
      (const float*)d_in[2],  (const float*)d_in[3],
      (const float*)d_in[4],  (const float*)d_in[5],
      (const float*)d_in[6],  (const float*)d_in[7],
      (const float*)d_in[11],
      (const float*)d_in[12], (const float*)d_in[13],
      (const float*)d_in[14], (const float*)d_in[15],
      (const float*)d_in[16], (const float*)d_in[17],
      (const float*)d_in[18], (const float*)d_in[19],
      (const float*)d_in[20], (const float*)d_in[21],
      (const float*)d_in[22], (const float*)d_in[23],
      (const float*)d_in[27],
      (const float*)d_in[28], (const float*)d_in[29],
      fE, fD, pe,
      (float*)d_out);
}